// Round 4
// baseline (592.590 us; speedup 1.0000x reference)
//
#include <hip/hip_runtime.h>
#include <cstdint>

// out = G @ (x @ W^T + b)      [8192,8192] @ [8192,128]
// mask is ignored: mask == (G==0), so where(mask,0,G) == G identically.
#define NN 8192   // nodes
#define KD 256    // in_dim
#define HD 128    // hidden

#define SPLITK 4
#define KS (NN / SPLITK)   // 2048 k per block
#define NS (KS / 32)       // 64 steps of k=32

typedef __attribute__((ext_vector_type(4))) float   f32x4;
typedef __attribute__((ext_vector_type(8))) __bf16  bf16x8;
typedef __attribute__((ext_vector_type(8))) unsigned short ushort8;

// fp32 -> bf16 round-to-nearest-even
static __device__ __forceinline__ unsigned short f2bf(float f) {
  unsigned u = __builtin_bit_cast(unsigned, f);
  u += 0x7FFFu + ((u >> 16) & 1u);
  return (unsigned short)(u >> 16);
}

static __device__ __forceinline__ bf16x8 pack8(const float4 a, const float4 b) {
  ushort8 u;
  u[0] = f2bf(a.x); u[1] = f2bf(a.y); u[2] = f2bf(a.z); u[3] = f2bf(a.w);
  u[4] = f2bf(b.x); u[5] = f2bf(b.y); u[6] = f2bf(b.z); u[7] = f2bf(b.w);
  return __builtin_bit_cast(bf16x8, u);
}

// ---------------------------------------------------------------------------
// Kernel A: ht = (x @ W^T + b)^T in k-octet-major bf16 layout:
//   element (hidden n, node m) at ht[(m>>3)*HD*8 + n*8 + (m&7)]
// so spmm's B-fragment (col n, node-octet o) is one contiguous uint4.
// 512 blocks x 64 thr (1 wave, 16 nodes each).
// ---------------------------------------------------------------------------
__global__ __launch_bounds__(64) void fc_ht_kernel(
    const float* __restrict__ x, const float* __restrict__ W,
    const float* __restrict__ bias, unsigned short* __restrict__ ht)
{
  const int lane = threadIdx.x & 63;
  const int l15  = lane & 15;
  const int lq   = lane >> 4;
  const int m0   = blockIdx.x * 16;

  f32x4 acc[8];
#pragma unroll
  for (int t = 0; t < 8; ++t) acc[t] = (f32x4)0.0f;

  const float* xr = x + (size_t)(m0 + l15) * KD;
#pragma unroll 1
  for (int s = 0; s < KD / 32; ++s) {
    const int k = s * 32 + lq * 8;
    const bf16x8 af = pack8(*(const float4*)(xr + k), *(const float4*)(xr + k + 4));
#pragma unroll
    for (int t = 0; t < 8; ++t) {
      const float* wr = W + (size_t)(t * 16 + l15) * KD + k;
      const bf16x8 bfr = pack8(*(const float4*)wr, *(const float4*)(wr + 4));
      acc[t] = __builtin_amdgcn_mfma_f32_16x16x32_bf16(af, bfr, acc[t], 0, 0, 0);
    }
  }

  // C/D layout: col n = t*16 + (lane&15), rows m = m0 + lq*4 + r (r = reg).
  // Octet o = m>>3 = m0/8 + (lq>>1); slot = (lq&1)*4 + r  -> one uint2 store.
#pragma unroll
  for (int t = 0; t < 8; ++t) {
    const int n  = t * 16 + l15;
    const float bv = bias[n];
    const size_t o = (size_t)(m0 >> 3) + (lq >> 1);
    uint2 v;
    v.x = (unsigned)f2bf(acc[t][0] + bv) | ((unsigned)f2bf(acc[t][1] + bv) << 16);
    v.y = (unsigned)f2bf(acc[t][2] + bv) | ((unsigned)f2bf(acc[t][3] + bv) << 16);
    *(uint2*)(ht + o * HD * 8 + n * 8 + (lq & 1) * 4) = v;
  }
}

// ---------------------------------------------------------------------------
// Kernel B: barrier-free register-streaming spmm.
// 2048 blocks = 512 row-tiles x SPLITK; block = 16 rows x 128 cols, 4 waves;
// wave w owns cols w*32 (2 frags, 8 acc VGPRs). All 4 waves load the SAME
// G fragment (L1 hits after the first). 2-deep register rotation, ~52 VGPRs,
// no LDS, no __syncthreads — 24 waves/CU of TLP keep HBM saturated.
// Split-K partials to P (plain stores); reduce_kernel sums.
// ---------------------------------------------------------------------------
__global__ __launch_bounds__(256, 6) void spmm_kernel(
    const float* __restrict__ G, const unsigned short* __restrict__ ht,
    float* __restrict__ P)
{
  const int lane = threadIdx.x & 63;
  const int wave = threadIdx.x >> 6;
  const int l15  = lane & 15;
  const int lq   = lane >> 4;
  const int rt   = blockIdx.x >> 2;    // 0..511 row-tile
  const int ks   = blockIdx.x & 3;     // k-stripe (== XCD&3: per-XCD ht locality)
  const int m0   = rt * 16;
  const int kb0  = ks * KS;
  const int n0   = wave * 32;

  // A-frag: G[m0+l15][kb0 + s*32 + lq*8 .. +8]
  const float* gp = G + (size_t)(m0 + l15) * NN + kb0 + lq * 8;
  // B-frag t: ht octet o = kb0/8 + s*4 + lq, col n0 + t*16 + l15 (uint4 units)
  const uint4* hq = (const uint4*)ht + ((size_t)(kb0 >> 3) + lq) * HD + n0 + l15;

  f32x4 acc[2];
  acc[0] = (f32x4)0.0f; acc[1] = (f32x4)0.0f;

  float4 gA0, gA1, gB0, gB1;
  uint4  hA0, hA1, hB0, hB1;

  // prologue: step 0 -> A-set
  gA0 = *(const float4*)(gp);
  gA1 = *(const float4*)(gp + 4);
  hA0 = hq[0];
  hA1 = hq[16];

#pragma unroll 1
  for (int s = 0; s < NS; s += 2) {
    // prefetch step s+1 -> B-set (NS even => always valid)
    {
      const float* g1 = gp + (size_t)(s + 1) * 32;
      gB0 = *(const float4*)(g1);
      gB1 = *(const float4*)(g1 + 4);
      const uint4* h1 = hq + (size_t)(s + 1) * 4 * HD;
      hB0 = h1[0];
      hB1 = h1[16];
    }
    {
      const bf16x8 af = pack8(gA0, gA1);
      acc[0] = __builtin_amdgcn_mfma_f32_16x16x32_bf16(
          af, __builtin_bit_cast(bf16x8, hA0), acc[0], 0, 0, 0);
      acc[1] = __builtin_amdgcn_mfma_f32_16x16x32_bf16(
          af, __builtin_bit_cast(bf16x8, hA1), acc[1], 0, 0, 0);
    }
    // prefetch step s+2 -> A-set
    if (s + 2 < NS) {
      const float* g2 = gp + (size_t)(s + 2) * 32;
      gA0 = *(const float4*)(g2);
      gA1 = *(const float4*)(g2 + 4);
      const uint4* h2 = hq + (size_t)(s + 2) * 4 * HD;
      hA0 = h2[0];
      hA1 = h2[16];
    }
    {
      const bf16x8 af = pack8(gB0, gB1);
      acc[0] = __builtin_amdgcn_mfma_f32_16x16x32_bf16(
          af, __builtin_bit_cast(bf16x8, hB0), acc[0], 0, 0, 0);
      acc[1] = __builtin_amdgcn_mfma_f32_16x16x32_bf16(
          af, __builtin_bit_cast(bf16x8, hB1), acc[1], 0, 0, 0);
    }
  }

  // epilogue: P[ks][m][n] plain stores. rows m = m0 + lq*4 + r, col per frag t.
  float* pp = P + ((size_t)ks * NN + m0 + lq * 4) * HD + n0 + l15;
#pragma unroll
  for (int t = 0; t < 2; ++t)
#pragma unroll
    for (int r = 0; r < 4; ++r)
      pp[(size_t)r * HD + t * 16] = acc[t][r];
}

// ---------------------------------------------------------------------------
// Kernel C: out[m][n] = sum_ks P[ks][m][n].  20 MB traffic, ~5 us.
// ---------------------------------------------------------------------------
__global__ __launch_bounds__(256) void reduce_kernel(
    const f32x4* __restrict__ P, f32x4* __restrict__ out)
{
  const int idx = blockIdx.x * 256 + threadIdx.x;   // 0..262143 float4s
  const int S = NN * HD / 4;
  f32x4 s = P[idx];
#pragma unroll
  for (int k = 1; k < SPLITK; ++k) s += P[(size_t)k * S + idx];
  out[idx] = s;
}

extern "C" void kernel_launch(void* const* d_in, const int* in_sizes, int n_in,
                              void* d_out, int out_size, void* d_ws, size_t ws_size,
                              hipStream_t stream) {
  const float* x = (const float*)d_in[0];
  const float* G = (const float*)d_in[1];
  // d_in[2] = mask: NEVER read. mask == (G==0) => where(mask,0,G) == G.
  const float* W = (const float*)d_in[3];
  const float* b = (const float*)d_in[4];
  float* out = (float*)d_out;

  unsigned short* ht = (unsigned short*)d_ws;                  // 2 MB
  float* P = (float*)((char*)d_ws + (4u << 20));               // 16 MB partials

  fc_ht_kernel<<<NN / 16, 64, 0, stream>>>(x, W, b, ht);
  spmm_kernel<<<(NN / 16) * SPLITK, 256, 0, stream>>>(G, ht, P);
  reduce_kernel<<<NN * HD / 4 / 256, 256, 0, stream>>>((const f32x4*)P, (f32x4*)out);
}

// Round 5
// 558.328 us; speedup vs baseline: 1.0614x; 1.0614x over previous
//
#include <hip/hip_runtime.h>
#include <cstdint>

// out = G @ (x @ W^T + b)      [8192,8192] @ [8192,128]
// mask is ignored: mask == (G==0), so where(mask,0,G) == G identically.
#define NN 8192   // nodes
#define KD 256    // in_dim
#define HD 128    // hidden

#define SPLITK 8
#define KS (NN / SPLITK)   // 1024 k per block
#define BK 32              // k per pipeline step
#define NSTEP (KS / BK)    // 32 steps

typedef __attribute__((ext_vector_type(4))) float   f32x4;
typedef __attribute__((ext_vector_type(8))) __bf16  bf16x8;
typedef __attribute__((ext_vector_type(8))) unsigned short ushort8;

// fp32 -> bf16 round-to-nearest-even
static __device__ __forceinline__ unsigned short f2bf(float f) {
  unsigned u = __builtin_bit_cast(unsigned, f);
  u += 0x7FFFu + ((u >> 16) & 1u);
  return (unsigned short)(u >> 16);
}

static __device__ __forceinline__ bf16x8 pack8(const float4 a, const float4 b) {
  ushort8 u;
  u[0] = f2bf(a.x); u[1] = f2bf(a.y); u[2] = f2bf(a.z); u[3] = f2bf(a.w);
  u[4] = f2bf(b.x); u[5] = f2bf(b.y); u[6] = f2bf(b.z); u[7] = f2bf(b.w);
  return __builtin_bit_cast(bf16x8, u);
}

#define GLD_LDS16(g, l)                                                        \
  __builtin_amdgcn_global_load_lds(                                            \
      (const __attribute__((address_space(1))) void*)(g),                      \
      (__attribute__((address_space(3))) void*)(l), 16, 0, 0)

// ---------------------------------------------------------------------------
// Kernel A: ht[n][m] = sum_k x[m][k]*W[n][k] + b[n], bf16, [HD][NN].
// ---------------------------------------------------------------------------
__global__ __launch_bounds__(64) void fc_ht_kernel(
    const float* __restrict__ x, const float* __restrict__ W,
    const float* __restrict__ bias, unsigned short* __restrict__ ht)
{
  const int lane = threadIdx.x & 63;
  const int l15  = lane & 15;
  const int lq   = lane >> 4;
  const int m0   = blockIdx.x * 16;

  f32x4 acc[8];
#pragma unroll
  for (int t = 0; t < 8; ++t) acc[t] = (f32x4)0.0f;

  const float* xr = x + (size_t)(m0 + l15) * KD;
#pragma unroll 1
  for (int s = 0; s < KD / 32; ++s) {
    const int k = s * 32 + lq * 8;
    const bf16x8 af = pack8(*(const float4*)(xr + k), *(const float4*)(xr + k + 4));
#pragma unroll
    for (int t = 0; t < 8; ++t) {
      const float* wr = W + (size_t)(t * 16 + l15) * KD + k;
      const bf16x8 bfr = pack8(*(const float4*)wr, *(const float4*)(wr + 4));
      acc[t] = __builtin_amdgcn_mfma_f32_16x16x32_bf16(af, bfr, acc[t], 0, 0, 0);
    }
  }

  // C/D layout: col = lane&15, row = (lane>>4)*4 + reg.
#pragma unroll
  for (int t = 0; t < 8; ++t) {
    const int n  = t * 16 + l15;
    const float bv = bias[n];
    const int mr = m0 + lq * 4;
    uint2 v;
    v.x = (unsigned)f2bf(acc[t][0] + bv) | ((unsigned)f2bf(acc[t][1] + bv) << 16);
    v.y = (unsigned)f2bf(acc[t][2] + bv) | ((unsigned)f2bf(acc[t][3] + bv) << 16);
    *(uint2*)(ht + (size_t)n * NN + mr) = v;
  }
}

// ---------------------------------------------------------------------------
// Kernel B: 3-deep LDS ring, AITER-style fine-grained waitcnt.
// 1024 blocks = 128 M-tiles x SPLITK, 256 thr (4 waves), 64x128 tile.
// Per step: raw `s_waitcnt vmcnt(4); s_barrier` (drains ONLY stage s; stage
// s+1 stays in flight across the barrier), then stage step s+2 into the ring,
// then ds_read/pack/8xMFMA on step s. Stage index wraps mod NSTEP so the
// vmcnt arithmetic holds on the final iterations (harmless re-reads).
// XOR swizzles (measured 0 bank conflicts in R3):
//   G  (64 r x 8 c16):  phys c holds global c ^ (r&7)
//   ht (128 r x 4 c16): phys c holds global c ^ ((r>>1)&3)
// LDS = 3 x (8KB G + 8KB ht) = 48KB -> 3 blocks/CU, 12 waves/CU.
// ---------------------------------------------------------------------------
__global__ __launch_bounds__(256, 3) void spmm_kernel(
    const float* __restrict__ G, const unsigned short* __restrict__ ht,
    float* __restrict__ P)
{
  __shared__ float          gsh[3 * 64 * BK];   // 3 x 8 KB
  __shared__ unsigned short hsh[3 * HD * BK];   // 3 x 8 KB

  const int tid   = threadIdx.x;
  const int lane  = tid & 63;
  const int wave  = tid >> 6;
  const int l15   = lane & 15;
  const int lq    = lane >> 4;
  const int mtile = blockIdx.x >> 3;   // 0..127
  const int ks    = blockIdx.x & 7;
  const int m0    = mtile * 64;
  const int kb0   = ks * KS;

  f32x4 acc[8];
#pragma unroll
  for (int t = 0; t < 8; ++t) acc[t] = (f32x4)0.0f;

#define STAGE(s_, gofs_, hofs_)                                                 \
  do {                                                                          \
    const int kb = kb0 + (s_) * BK;                                             \
    _Pragma("unroll")                                                           \
    for (int i = 0; i < 2; ++i) {                                               \
      const int e = i * 256 + tid;                                              \
      const int r = e >> 3, c = e & 7;                                          \
      GLD_LDS16(G + (size_t)(m0 + r) * NN + kb + ((c ^ (r & 7)) * 4),           \
                &gsh[(gofs_) + e * 4]);                                         \
    }                                                                           \
    _Pragma("unroll")                                                           \
    for (int i = 0; i < 2; ++i) {                                               \
      const int e = i * 256 + tid;                                              \
      const int r = e >> 2, c = e & 3;                                          \
      GLD_LDS16(ht + (size_t)r * NN + kb + ((c ^ ((r >> 1) & 3)) * 8),          \
                &hsh[(hofs_) + e * 8]);                                         \
    }                                                                           \
  } while (0)

  // prologue: stages 0,1 into slots 0,1
  STAGE(0, 0, 0);
  STAGE(1, 2048, 4096);

  // read-side swizzled chunk indices (loop-invariant)
  const int gsw0 = (lq * 2 + 0) ^ (l15 & 7);
  const int gsw1 = (lq * 2 + 1) ^ (l15 & 7);
  const int hsw  = lq ^ ((l15 >> 1) & 3);
  const int gr   = wave * 16 + l15;

  int gc = 0, hc = 0;            // consume slot offsets
  int gs = 4096, hs = 8192;      // stage slot offsets (slot 2)

#pragma unroll 1
  for (int s = 0; s < NSTEP; ++s) {
    // drain ONLY stage s (4 insts); stage s+1 (4 insts) stays in flight.
    asm volatile("s_waitcnt vmcnt(4)\n\ts_barrier" ::: "memory");

    int sk = s + 2;
    if (sk >= NSTEP) sk -= NSTEP;   // wrap: harmless re-read, keeps vmcnt math
    STAGE(sk, gs, hs);

    const float4 ga0 = *(const float4*)&gsh[gc + gr * 32 + gsw0 * 4];
    const float4 ga1 = *(const float4*)&gsh[gc + gr * 32 + gsw1 * 4];
    const bf16x8 af = pack8(ga0, ga1);

    uint4 hb[8];
#pragma unroll
    for (int t = 0; t < 8; ++t)
      hb[t] = *(const uint4*)&hsh[hc + (t * 16 + l15) * BK + hsw * 8];
#pragma unroll
    for (int t = 0; t < 8; ++t)
      acc[t] = __builtin_amdgcn_mfma_f32_16x16x32_bf16(
          af, __builtin_bit_cast(bf16x8, hb[t]), acc[t], 0, 0, 0);

    gc += 2048; if (gc == 6144) gc = 0;
    hc += 4096; if (hc == 12288) hc = 0;
    gs += 2048; if (gs == 6144) gs = 0;
    hs += 4096; if (hs == 12288) hs = 0;
  }

  // epilogue: plain stores of split-K partials, P[ks][m][n]
  const int mr = m0 + wave * 16 + lq * 4;
  float* __restrict__ pp = P + ((size_t)ks * NN + mr) * HD;
#pragma unroll
  for (int t = 0; t < 8; ++t) {
    const int n = t * 16 + l15;
#pragma unroll
    for (int r = 0; r < 4; ++r)
      pp[(size_t)r * HD + n] = acc[t][r];
  }
}

// ---------------------------------------------------------------------------
// Kernel C: out[m][n] = sum_ks P[ks][m][n].
// ---------------------------------------------------------------------------
__global__ __launch_bounds__(256) void reduce_kernel(
    const f32x4* __restrict__ P, f32x4* __restrict__ out)
{
  const int idx = blockIdx.x * 256 + threadIdx.x;   // 0..262143 float4s
  const int S = NN * HD / 4;
  f32x4 s = P[idx];
#pragma unroll
  for (int k = 1; k < SPLITK; ++k) s += P[(size_t)k * S + idx];
  out[idx] = s;
}

extern "C" void kernel_launch(void* const* d_in, const int* in_sizes, int n_in,
                              void* d_out, int out_size, void* d_ws, size_t ws_size,
                              hipStream_t stream) {
  const float* x = (const float*)d_in[0];
  const float* G = (const float*)d_in[1];
  // d_in[2] = mask: NEVER read. mask == (G==0) => where(mask,0,G) == G.
  const float* W = (const float*)d_in[3];
  const float* b = (const float*)d_in[4];
  float* out = (float*)d_out;

  unsigned short* ht = (unsigned short*)d_ws;                  // 2 MB
  float* P = (float*)((char*)d_ws + (4u << 20));               // 32 MB partials

  fc_ht_kernel<<<NN / 16, 64, 0, stream>>>(x, W, b, ht);
  spmm_kernel<<<(NN / 64) * SPLITK, 256, 0, stream>>>(G, ht, P);
  reduce_kernel<<<NN * HD / 4 / 256, 256, 0, stream>>>((const f32x4*)P, (f32x4*)out);
}

// Round 6
// 523.345 us; speedup vs baseline: 1.1323x; 1.0668x over previous
//
#include <hip/hip_runtime.h>
#include <cstdint>

// out = G @ (x @ W^T + b)      [8192,8192] @ [8192,128]
// mask is ignored: mask == (G==0), so where(mask,0,G) == G identically.
#define NN 8192   // nodes
#define KD 256    // in_dim
#define HD 128    // hidden

#define SPLITK 8
#define KS (NN / SPLITK)   // 1024 k per block
#define BK 32              // k per pipeline step
#define NSTEP (KS / BK)    // 32 steps

typedef __attribute__((ext_vector_type(4))) float   f32x4;
typedef __attribute__((ext_vector_type(8))) __bf16  bf16x8;
typedef __attribute__((ext_vector_type(8))) unsigned short ushort8;

// fp32 -> bf16 round-to-nearest-even
static __device__ __forceinline__ unsigned short f2bf(float f) {
  unsigned u = __builtin_bit_cast(unsigned, f);
  u += 0x7FFFu + ((u >> 16) & 1u);
  return (unsigned short)(u >> 16);
}

static __device__ __forceinline__ bf16x8 pack8(const float4 a, const float4 b) {
  ushort8 u;
  u[0] = f2bf(a.x); u[1] = f2bf(a.y); u[2] = f2bf(a.z); u[3] = f2bf(a.w);
  u[4] = f2bf(b.x); u[5] = f2bf(b.y); u[6] = f2bf(b.z); u[7] = f2bf(b.w);
  return __builtin_bit_cast(bf16x8, u);
}

#define GLD_LDS16(g, l)                                                        \
  __builtin_amdgcn_global_load_lds(                                            \
      (const __attribute__((address_space(1))) void*)(g),                      \
      (__attribute__((address_space(3))) void*)(l), 16, 0, 0)

// ---------------------------------------------------------------------------
// Kernel A: ht[n][m] = sum_k x[m][k]*W[n][k] + b[n], bf16, [HD][NN].
// ---------------------------------------------------------------------------
__global__ __launch_bounds__(64) void fc_ht_kernel(
    const float* __restrict__ x, const float* __restrict__ W,
    const float* __restrict__ bias, unsigned short* __restrict__ ht)
{
  const int lane = threadIdx.x & 63;
  const int l15  = lane & 15;
  const int lq   = lane >> 4;
  const int m0   = blockIdx.x * 16;

  f32x4 acc[8];
#pragma unroll
  for (int t = 0; t < 8; ++t) acc[t] = (f32x4)0.0f;

  const float* xr = x + (size_t)(m0 + l15) * KD;
#pragma unroll 1
  for (int s = 0; s < KD / 32; ++s) {
    const int k = s * 32 + lq * 8;
    const bf16x8 af = pack8(*(const float4*)(xr + k), *(const float4*)(xr + k + 4));
#pragma unroll
    for (int t = 0; t < 8; ++t) {
      const float* wr = W + (size_t)(t * 16 + l15) * KD + k;
      const bf16x8 bfr = pack8(*(const float4*)wr, *(const float4*)(wr + 4));
      acc[t] = __builtin_amdgcn_mfma_f32_16x16x32_bf16(af, bfr, acc[t], 0, 0, 0);
    }
  }

  // C/D layout: col = lane&15, row = (lane>>4)*4 + reg.
#pragma unroll
  for (int t = 0; t < 8; ++t) {
    const int n  = t * 16 + l15;
    const float bv = bias[n];
    const int mr = m0 + lq * 4;
    uint2 v;
    v.x = (unsigned)f2bf(acc[t][0] + bv) | ((unsigned)f2bf(acc[t][1] + bv) << 16);
    v.y = (unsigned)f2bf(acc[t][2] + bv) | ((unsigned)f2bf(acc[t][3] + bv) << 16);
    *(uint2*)(ht + (size_t)n * NN + mr) = v;
  }
}

// ---------------------------------------------------------------------------
// Kernel B: R3 structure (double-buffered LDS, __syncthreads per step)
// + PER-BLOCK K-PHASE ROTATION. All prior versions read G in device-wide
// lockstep at addresses sharing the same low-15 bits (row stride 32 KB =
// 2^15) -> all instantaneous requests map to few HBM channels/banks ->
// ~1.7 TB/s wall. Each block now traverses its 32 steps starting at phase
// (mtile & 31): 8 ks-stripes x 32 phases = 256 distinct 128B offsets =
// full 32 KB row footprint live at once -> all channels busy.
// Summation order per output changes (fp32 acc reorder) -> ~1 ulp jitter.
// XOR swizzles (verified 0 bank conflicts in R3) unchanged.
// ---------------------------------------------------------------------------
__global__ __launch_bounds__(256, 4) void spmm_kernel(
    const float* __restrict__ G, const unsigned short* __restrict__ ht,
    float* __restrict__ P)
{
  __shared__ float          gsh[2][64 * BK];   // 8 KB per buffer
  __shared__ unsigned short hsh[2][HD * BK];   // 8 KB per buffer

  const int tid   = threadIdx.x;
  const int lane  = tid & 63;
  const int wave  = tid >> 6;
  const int l15   = lane & 15;
  const int lq    = lane >> 4;
  const int mtile = blockIdx.x >> 3;   // 0..127
  const int ks    = blockIdx.x & 7;
  const int m0    = mtile * 64;
  const int kb0   = ks * KS;
  const int phase = mtile & (NSTEP - 1);

  f32x4 acc[8];
#pragma unroll
  for (int t = 0; t < 8; ++t) acc[t] = (f32x4)0.0f;

  // logical step = (s + phase) mod NSTEP; staged and consumed in that order.
#define STAGE(s_, buf_)                                                         \
  do {                                                                          \
    const int kb = kb0 + (((s_) + phase) & (NSTEP - 1)) * BK;                   \
    _Pragma("unroll")                                                           \
    for (int i = 0; i < 2; ++i) {                                               \
      const int e = i * 256 + tid;                                              \
      const int r = e >> 3, c = e & 7;                                          \
      GLD_LDS16(G + (size_t)(m0 + r) * NN + kb + ((c ^ (r & 7)) * 4),           \
                &gsh[buf_][e * 4]);                                             \
    }                                                                           \
    _Pragma("unroll")                                                           \
    for (int i = 0; i < 2; ++i) {                                               \
      const int e = i * 256 + tid;                                              \
      const int r = e >> 2, c = e & 3;                                          \
      GLD_LDS16(ht + (size_t)r * NN + kb + ((c ^ ((r >> 1) & 3)) * 8),          \
                &hsh[buf_][e * 8]);                                             \
    }                                                                           \
  } while (0)

  STAGE(0, 0);

  // read-side swizzled chunk indices (loop-invariant)
  const int gsw0 = (lq * 2 + 0) ^ (l15 & 7);
  const int gsw1 = (lq * 2 + 1) ^ (l15 & 7);
  const int hsw  = lq ^ ((l15 >> 1) & 3);
  const int gr   = wave * 16 + l15;

#pragma unroll 1
  for (int s = 0; s < NSTEP; ++s) {
    __syncthreads();                      // vmcnt(0) drain: buf[s&1] ready
    if (s + 1 < NSTEP) STAGE(s + 1, (s + 1) & 1);

    const int b = s & 1;
    const float4 ga0 = *(const float4*)&gsh[b][gr * 32 + gsw0 * 4];
    const float4 ga1 = *(const float4*)&gsh[b][gr * 32 + gsw1 * 4];
    const bf16x8 af = pack8(ga0, ga1);

    uint4 hb[8];
#pragma unroll
    for (int t = 0; t < 8; ++t)
      hb[t] = *(const uint4*)&hsh[b][(t * 16 + l15) * BK + hsw * 8];
#pragma unroll
    for (int t = 0; t < 8; ++t)
      acc[t] = __builtin_amdgcn_mfma_f32_16x16x32_bf16(
          af, __builtin_bit_cast(bf16x8, hb[t]), acc[t], 0, 0, 0);
  }

  // epilogue: plain stores of split-K partials, P[ks][m][n]
  const int mr = m0 + wave * 16 + lq * 4;
  float* __restrict__ pp = P + ((size_t)ks * NN + mr) * HD;
#pragma unroll
  for (int t = 0; t < 8; ++t) {
    const int n = t * 16 + l15;
#pragma unroll
    for (int r = 0; r < 4; ++r)
      pp[(size_t)r * HD + n] = acc[t][r];
  }
}

// ---------------------------------------------------------------------------
// Kernel C: out[m][n] = sum_ks P[ks][m][n].
// ---------------------------------------------------------------------------
__global__ __launch_bounds__(256) void reduce_kernel(
    const f32x4* __restrict__ P, f32x4* __restrict__ out)
{
  const int idx = blockIdx.x * 256 + threadIdx.x;   // 0..262143 float4s
  const int S = NN * HD / 4;
  f32x4 s = P[idx];
#pragma unroll
  for (int k = 1; k < SPLITK; ++k) s += P[(size_t)k * S + idx];
  out[idx] = s;
}

extern "C" void kernel_launch(void* const* d_in, const int* in_sizes, int n_in,
                              void* d_out, int out_size, void* d_ws, size_t ws_size,
                              hipStream_t stream) {
  const float* x = (const float*)d_in[0];
  const float* G = (const float*)d_in[1];
  // d_in[2] = mask: NEVER read. mask == (G==0) => where(mask,0,G) == G.
  const float* W = (const float*)d_in[3];
  const float* b = (const float*)d_in[4];
  float* out = (float*)d_out;

  unsigned short* ht = (unsigned short*)d_ws;                  // 2 MB
  float* P = (float*)((char*)d_ws + (4u << 20));               // 32 MB partials

  fc_ht_kernel<<<NN / 16, 64, 0, stream>>>(x, W, b, ht);
  spmm_kernel<<<(NN / 64) * SPLITK, 256, 0, stream>>>(G, ht, P);
  reduce_kernel<<<NN * HD / 4 / 256, 256, 0, stream>>>((const f32x4*)P, (f32x4*)out);
}